// Round 8
// baseline (171.868 us; speedup 1.0000x reference)
//
#include <hip/hip_runtime.h>
#include <cstdint>
#include <cstddef>

#define BATCH   16384
#define NFEAT   2048
#define KD      1024     // num_used (= K of GEMM1, = rows of W)
#define NNODE   1024     // num_leaves / node columns
#define NCLS    100

typedef __attribute__((ext_vector_type(8))) __bf16 bf16x8;
typedef __attribute__((ext_vector_type(4))) float f32x4;
typedef __attribute__((ext_vector_type(4))) unsigned int u32x4;

__device__ __forceinline__ unsigned short f2bf(float f) {
  union { float f; unsigned int u; } v; v.f = f;
  unsigned int r = v.u + 0x7FFFu + ((v.u >> 16) & 1u);
  return (unsigned short)(r >> 16);
}
__device__ __forceinline__ float bf2f(unsigned short h) {
  union { unsigned int u; float f; } v; v.u = ((unsigned int)h) << 16;
  return v.f;
}

__device__ __forceinline__ void gload_lds16(const void* g, void* l) {
  __builtin_amdgcn_global_load_lds((__attribute__((address_space(1))) void*)g,
                                   (__attribute__((address_space(3))) void*)l,
                                   16, 0, 0);
}

__device__ __forceinline__ bf16x8 ld_frag(const unsigned short* p) {
  return __builtin_bit_cast(bf16x8, *(const u32x4*)p);
}

// ---- prep: extract idx[i] = argmax of one-hot mask row i ----
__global__ void k_idx(const float* __restrict__ mask, int* __restrict__ idx) {
  int r = blockIdx.x, t = threadIdx.x;
  for (int c = t; c < NFEAT; c += 256)
    if (__builtin_nontemporal_load(&mask[(size_t)r * NFEAT + c]) > 0.5f) idx[r] = c;
}

// ---- prep: WT[n][k] = bf16(W[k][n]) ----
__global__ void k_wt(const float* __restrict__ W, unsigned short* __restrict__ WT) {
  __shared__ float tile[32][33];
  int n0 = blockIdx.x * 32, k0 = blockIdx.y * 32;
  int tx = threadIdx.x, ty = threadIdx.y; // (32, 8)
  for (int i = ty; i < 32; i += 8)
    tile[i][tx] = W[(size_t)(k0 + i) * NNODE + n0 + tx];
  __syncthreads();
  for (int i = ty; i < 32; i += 8)
    WT[(size_t)(n0 + i) * KD + k0 + tx] = f2bf(tile[tx][i]);
}

// ---- prep: PT[n][l] = bf16(softmax(pi[l,:])[n]), zero-padded to 128 rows ----
__global__ void k_probs(const float* __restrict__ pi, unsigned short* __restrict__ PT) {
  int l = blockIdx.x, t = threadIdx.x; // 64 threads
  float v0 = (t < NCLS) ? pi[(size_t)l * NCLS + t] : -1e30f;
  float v1 = (t + 64 < NCLS) ? pi[(size_t)l * NCLS + t + 64] : -1e30f;
  float m = fmaxf(v0, v1);
  for (int o = 32; o; o >>= 1) m = fmaxf(m, __shfl_xor(m, o));
  float e0 = (t < NCLS) ? __expf(v0 - m) : 0.f;
  float e1 = (t + 64 < NCLS) ? __expf(v1 - m) : 0.f;
  float s = e0 + e1;
  for (int o = 32; o; o >>= 1) s += __shfl_xor(s, o);
  float inv = 1.f / s;
  PT[(size_t)t * NNODE + l] = f2bf(e0 * inv);
  PT[(size_t)(t + 64) * NNODE + l] = f2bf(e1 * inv);
}

// ---- gather: X[row][i] = bf16(features[row][idx[i]]) ----
// Block->row mapping XCD-aligned (stripe s written from XCD s%8, matching
// gemm1's m-block XCD). Features reads are non-temporal: read-once stream,
// keep L2 for the X being written + WT/PT needed by gemm1 next.
__global__ void k_gather(const float* __restrict__ F, const int* __restrict__ idx,
                         unsigned short* __restrict__ X) {
  __shared__ int idxs[KD];
  int b = blockIdx.x, t = threadIdx.x;
  int row = ((b & 7) << 7) + ((b >> 10) << 10) + ((b >> 3) & 127);
  for (int j = t; j < KD; j += 256) idxs[j] = idx[j];
  __syncthreads();
  const float* frow = F + (size_t)row * NFEAT;
  int i0 = t * 4;
  ushort4 o;
  o.x = f2bf(__builtin_nontemporal_load(&frow[idxs[i0 + 0]]));
  o.y = f2bf(__builtin_nontemporal_load(&frow[idxs[i0 + 1]]));
  o.z = f2bf(__builtin_nontemporal_load(&frow[idxs[i0 + 2]]));
  o.w = f2bf(__builtin_nontemporal_load(&frow[idxs[i0 + 3]]));
  *(ushort4*)(X + (size_t)row * KD + i0) = o;
}

// ============ GEMM1: D = sigmoid(X @ WT^T + b) ============
// m97 structure: 128x128 tile, BK=64, 256 threads = 4 waves (2x2), wave tile
// 64x64 (acc 4x4). Single LDS buffer, 2-phase syncthreads loop.
// T2 XOR-swizzle via pre-swizzled source + swizzled ds_read.
// __launch_bounds__(256,4): 4 blocks/CU (verified: 42 us warm = ~810 TF).
__global__ __launch_bounds__(256, 4)
void k_gemm1(const unsigned short* __restrict__ A, const unsigned short* __restrict__ Bt,
             const float* __restrict__ bias, unsigned short* __restrict__ D) {
  __shared__ __align__(16) unsigned short As[128 * 64];
  __shared__ __align__(16) unsigned short Bs[128 * 64];
  const int t = threadIdx.x;
  const int lane = t & 63;
  const int wave = t >> 6;
  const int m0 = blockIdx.x * 128;
  const int n0 = blockIdx.y * 128;
  const int wm = (wave >> 1) * 64;
  const int wn = (wave & 1) * 64;
  const int cl = lane & 15;
  const int klb = (lane >> 4) * 8;
  const int rsel = (lane & 7) * 8;       // read-side swizzle (elems)

  const int sc = ((t & 7) ^ ((t >> 3) & 7)) * 8;  // pre-swizzled source col
  const unsigned short* Ab = A + (size_t)(m0 + (t >> 3)) * KD + sc;
  const unsigned short* Bb = Bt + (size_t)(n0 + (t >> 3)) * KD + sc;
  unsigned short* const Ad = As + (size_t)(t & ~63) * 8;
  unsigned short* const Bd = Bs + (size_t)(t & ~63) * 8;

  f32x4 acc[4][4];
#pragma unroll
  for (int i = 0; i < 4; ++i)
#pragma unroll
    for (int j = 0; j < 4; ++j) acc[i][j] = (f32x4)0.f;

  for (int kt = 0; kt < KD / 64; ++kt) {
    const int k0 = kt * 64;
#pragma unroll
    for (int j = 0; j < 4; ++j) {
      gload_lds16(Ab + (size_t)j * 32 * KD + k0, Ad + j * 2048);
      gload_lds16(Bb + (size_t)j * 32 * KD + k0, Bd + j * 2048);
    }
    __syncthreads();
#pragma unroll
    for (int kk = 0; kk < 2; ++kk) {
      bf16x8 af[4], bfr[4];
      const int kl = kk * 32 + klb;
#pragma unroll
      for (int n = 0; n < 4; ++n)
        bfr[n] = ld_frag(Bs + (wn + n * 16 + cl) * 64 + (kl ^ rsel));
#pragma unroll
      for (int m = 0; m < 4; ++m)
        af[m] = ld_frag(As + (wm + m * 16 + cl) * 64 + (kl ^ rsel));
      __builtin_amdgcn_s_setprio(1);
#pragma unroll
      for (int m = 0; m < 4; ++m)
#pragma unroll
        for (int n = 0; n < 4; ++n)
          acc[m][n] = __builtin_amdgcn_mfma_f32_16x16x32_bf16(af[m], bfr[n], acc[m][n], 0, 0, 0);
      __builtin_amdgcn_s_setprio(0);
    }
    __syncthreads();
  }

  // epilogue: sigmoid(acc + bias) -> bf16 D
  const int rq = lane >> 4;
#pragma unroll
  for (int n = 0; n < 4; ++n) {
    const int col = n0 + wn + n * 16 + cl;
    const float bv = bias[col];
#pragma unroll
    for (int m = 0; m < 4; ++m) {
      const int rbase = m0 + wm + m * 16 + rq * 4;
#pragma unroll
      for (int i = 0; i < 4; ++i) {
        float v = acc[m][n][i] + bv;
        float s = 1.0f / (1.0f + __expf(-v));
        D[(size_t)(rbase + i) * NNODE + col] = f2bf(s);
      }
    }
  }
}

// ============ k_rg2: fused route + GEMM2, 2 blocks/CU ============
// 512 blocks x 256 threads, 32 batch rows per block. LDS = Mu 64K + Bs 16K
// = 80K exactly -> 2 blocks/CU (launch_bounds(256,2)).
// Phase 1: routing reads d-values DIRECTLY from global D (L2/L3-hot, just
//          written by gemm1; ~176 independent loads/thread, MLP-covered),
//          writes mu to XOR-swizzled Mu (chunk ^= row&7 -> conflict-free
//          stride-1024 MFMA A-reads, 2-way only).
// Phase 2: out = Mu @ PT^T; B reg-prefetched one K-step ahead; nt-store out.
__global__ __launch_bounds__(256, 2)
void k_rg2(const unsigned short* __restrict__ D, const unsigned short* __restrict__ PT,
           float* __restrict__ outF) {
  __shared__ __align__(16) unsigned short Mu[32 * 1024];
  __shared__ __align__(16) unsigned short Bs[128 * 64];
  const int t = threadIdx.x;
  const int lane = t & 63;
  const int wave = t >> 6;
  const int m0 = blockIdx.x * 32;

  // ---- phase 1: route. thread -> (row = t>>3, octant = t&7), 128 leaves.
  {
    const int row = t >> 3;
    const unsigned short* drow = D + (size_t)(m0 + row) * NNODE;
    unsigned short* murow = Mu + row * 1024;
    const int rswz = (row & 7) << 3;            // elem-XOR for this row
    const int lb = (t & 7) * 128;
#pragma unroll
    for (int s = 0; s < 8; ++s) {
      const int lb16 = lb + s * 16;
      float P5 = 1.0f;
#pragma unroll
      for (int k = 0; k < 6; ++k) {
        int node = (1 << k) + (lb16 >> (10 - k));
        float d = bf2f(drow[node]);
        P5 *= ((lb16 >> (9 - k)) & 1) ? (1.0f - d) : d;
      }
#pragma unroll
      for (int gg = 0; gg < 4; ++gg) {
        const int lb4 = lb16 + gg * 4;
        float d6 = bf2f(drow[64 + (lb4 >> 4)]);
        float d7 = bf2f(drow[128 + (lb4 >> 3)]);
        float P7 = P5 * (((lb4 >> 3) & 1) ? (1.0f - d6) : d6)
                      * (((lb4 >> 2) & 1) ? (1.0f - d7) : d7);
        float d8 = bf2f(drow[256 + (lb4 >> 2)]);
        // d9 sibling pair: indices 512+(lb4>>1), +1 -> one aligned 4B load
        unsigned int d9u = *(const unsigned int*)(drow + 512 + (lb4 >> 1));
        float d9a = bf2f((unsigned short)(d9u & 0xFFFFu));
        float d9b = bf2f((unsigned short)(d9u >> 16));
        float P8a = P7 * d8, P8b = P7 * (1.0f - d8);
        ushort4 m4;
        m4.x = f2bf(P8a * d9a);
        m4.y = f2bf(P8a * (1.0f - d9a));
        m4.z = f2bf(P8b * d9b);
        m4.w = f2bf(P8b * (1.0f - d9b));
        *(ushort4*)(murow + (lb4 ^ rswz)) = m4;   // 4-aligned: XOR hits bits 3-5
      }
    }
  }
  __syncthreads();

  // ---- phase 2: GEMM. 4 waves: wm = (wave>>1)*16, wn = (wave&1)*64.
  const int cl = lane & 15;
  const int klb = (lane >> 4) * 8;
  const int rsel = (lane & 7) * 8;        // Bs read swizzle
  const int arsel = (cl & 7) * 8;         // Mu read swizzle (row = wm+cl, wm mult of 16)
  const int wm = (wave >> 1) * 16;
  const int wn = (wave & 1) * 64;
  // B staging: thread -> row br = t>>1, k-half bh = t&1 (4 chunks of 8).
  const int br = t >> 1, bh = t & 1;
  const unsigned short* Bg = PT + (size_t)br * NNODE + bh * 32;
  unsigned short* bw0 = Bs + br * 64 + (((bh * 4 + 0) ^ (br & 7)) * 8);
  unsigned short* bw1 = Bs + br * 64 + (((bh * 4 + 1) ^ (br & 7)) * 8);
  unsigned short* bw2 = Bs + br * 64 + (((bh * 4 + 2) ^ (br & 7)) * 8);
  unsigned short* bw3 = Bs + br * 64 + (((bh * 4 + 3) ^ (br & 7)) * 8);

  f32x4 acc[4];
#pragma unroll
  for (int n = 0; n < 4; ++n) acc[n] = (f32x4)0.f;

  u32x4 p0 = *(const u32x4*)(Bg + 0);
  u32x4 p1 = *(const u32x4*)(Bg + 8);
  u32x4 p2 = *(const u32x4*)(Bg + 16);
  u32x4 p3 = *(const u32x4*)(Bg + 24);

  for (int kt = 0; kt < 16; ++kt) {
    *(u32x4*)bw0 = p0; *(u32x4*)bw1 = p1; *(u32x4*)bw2 = p2; *(u32x4*)bw3 = p3;
    if (kt < 15) {
      const unsigned short* g = Bg + (kt + 1) * 64;
      p0 = *(const u32x4*)(g + 0);
      p1 = *(const u32x4*)(g + 8);
      p2 = *(const u32x4*)(g + 16);
      p3 = *(const u32x4*)(g + 24);
    }
    __syncthreads();
#pragma unroll
    for (int kk = 0; kk < 2; ++kk) {
      const int kl = kk * 32 + klb;
      bf16x8 a = ld_frag(Mu + (wm + cl) * 1024 + ((kt * 64 + kl) ^ arsel));
      bf16x8 bfr[4];
#pragma unroll
      for (int n = 0; n < 4; ++n)
        bfr[n] = ld_frag(Bs + (wn + n * 16 + cl) * 64 + (kl ^ rsel));
#pragma unroll
      for (int n = 0; n < 4; ++n)
        acc[n] = __builtin_amdgcn_mfma_f32_16x16x32_bf16(a, bfr[n], acc[n], 0, 0, 0);
    }
    __syncthreads();
  }

  const int rq = lane >> 4;
#pragma unroll
  for (int n = 0; n < 4; ++n) {
    int col = wn + n * 16 + cl;
    if (col < NCLS) {
#pragma unroll
      for (int i = 0; i < 4; ++i)
        __builtin_nontemporal_store(acc[n][i],
            &outF[(size_t)(m0 + wm + rq * 4 + i) * NCLS + col]);
    }
  }
}

extern "C" void kernel_launch(void* const* d_in, const int* in_sizes, int n_in,
                              void* d_out, int out_size, void* d_ws, size_t ws_size,
                              hipStream_t stream) {
  const float* features = (const float*)d_in[0]; // [16384][2048]
  const float* mask     = (const float*)d_in[1]; // [1024][2048]
  const float* W        = (const float*)d_in[2]; // [1024][1024]
  const float* bias     = (const float*)d_in[3]; // [1024]
  const float* pi       = (const float*)d_in[4]; // [1024][100]
  float* out = (float*)d_out;                    // [16384][100]

  char* ws = (char*)d_ws;
  int* idx           = (int*)ws;                                    // 4 KiB
  unsigned short* WT = (unsigned short*)(ws + 4096);                // 2 MiB [1024][1024]
  unsigned short* PT = (unsigned short*)(ws + 4096 + (1u << 21));   // 256 KiB [128][1024]
  unsigned short* X  = (unsigned short*)(ws + 4096 + (1u << 21) + (1u << 18)); // 32 MiB
  unsigned short* D  = (unsigned short*)(ws + 4096 + (1u << 21) + (1u << 18) + (1u << 25)); // 32 MiB

  // Small preps first; gather last before gemm1 so X is the freshest data in
  // cache (round-5/6 measurement: gemm1 42 us warm vs ~70 us cold).
  k_idx<<<dim3(KD), dim3(256), 0, stream>>>(mask, idx);
  k_wt<<<dim3(32, 32), dim3(32, 8), 0, stream>>>(W, WT);
  k_probs<<<dim3(NNODE), dim3(64), 0, stream>>>(pi, PT);
  k_gather<<<dim3(BATCH), dim3(256), 0, stream>>>(features, idx, X);
  k_gemm1<<<dim3(BATCH / 128, NNODE / 128), dim3(256), 0, stream>>>(X, WT, bias, D);
  k_rg2<<<dim3(BATCH / 32), dim3(256), 0, stream>>>(D, PT, out);
}

// Round 9
// 107.228 us; speedup vs baseline: 1.6028x; 1.6028x over previous
//
#include <hip/hip_runtime.h>
#include <cstdint>
#include <cstddef>

#define BATCH   16384
#define NFEAT   2048
#define KD      1024     // num_used (= K of GEMM1, = rows of W)
#define NNODE   1024     // num_leaves / node columns
#define NCLS    100

typedef __attribute__((ext_vector_type(8))) __bf16 bf16x8;
typedef __attribute__((ext_vector_type(4))) float f32x4;
typedef __attribute__((ext_vector_type(4))) unsigned int u32x4;

__device__ __forceinline__ unsigned short f2bf(float f) {
  union { float f; unsigned int u; } v; v.f = f;
  unsigned int r = v.u + 0x7FFFu + ((v.u >> 16) & 1u);
  return (unsigned short)(r >> 16);
}
__device__ __forceinline__ float bf2f(unsigned short h) {
  union { unsigned int u; float f; } v; v.u = ((unsigned int)h) << 16;
  return v.f;
}

__device__ __forceinline__ void gload_lds16(const void* g, void* l) {
  __builtin_amdgcn_global_load_lds((__attribute__((address_space(1))) void*)g,
                                   (__attribute__((address_space(3))) void*)l,
                                   16, 0, 0);
}

__device__ __forceinline__ bf16x8 ld_frag(const unsigned short* p) {
  return __builtin_bit_cast(bf16x8, *(const u32x4*)p);
}

// ---- prep: extract idx[i] = argmax of one-hot mask row i ----
__global__ void k_idx(const float* __restrict__ mask, int* __restrict__ idx) {
  int r = blockIdx.x, t = threadIdx.x;
  for (int c = t; c < NFEAT; c += 256)
    if (mask[(size_t)r * NFEAT + c] > 0.5f) idx[r] = c;
}

// ---- prep: WT[n][k] = bf16(W[k][n]) ----
__global__ void k_wt(const float* __restrict__ W, unsigned short* __restrict__ WT) {
  __shared__ float tile[32][33];
  int n0 = blockIdx.x * 32, k0 = blockIdx.y * 32;
  int tx = threadIdx.x, ty = threadIdx.y; // (32, 8)
  for (int i = ty; i < 32; i += 8)
    tile[i][tx] = W[(size_t)(k0 + i) * NNODE + n0 + tx];
  __syncthreads();
  for (int i = ty; i < 32; i += 8)
    WT[(size_t)(n0 + i) * KD + k0 + tx] = f2bf(tile[tx][i]);
}

// ---- prep: PT[n][l] = bf16(softmax(pi[l,:])[n]), zero-padded to 128 rows ----
__global__ void k_probs(const float* __restrict__ pi, unsigned short* __restrict__ PT) {
  int l = blockIdx.x, t = threadIdx.x; // 64 threads
  float v0 = (t < NCLS) ? pi[(size_t)l * NCLS + t] : -1e30f;
  float v1 = (t + 64 < NCLS) ? pi[(size_t)l * NCLS + t + 64] : -1e30f;
  float m = fmaxf(v0, v1);
  for (int o = 32; o; o >>= 1) m = fmaxf(m, __shfl_xor(m, o));
  float e0 = (t < NCLS) ? __expf(v0 - m) : 0.f;
  float e1 = (t + 64 < NCLS) ? __expf(v1 - m) : 0.f;
  float s = e0 + e1;
  for (int o = 32; o; o >>= 1) s += __shfl_xor(s, o);
  float inv = 1.f / s;
  PT[(size_t)t * NNODE + l] = f2bf(e0 * inv);
  PT[(size_t)(t + 64) * NNODE + l] = f2bf(e1 * inv);
}

// ---- gather: X[row][i] = bf16(features[row][idx[i]]) ----
// Round-9: full-row LDS staging. The 8 KB feature row is read COALESCED
// (float4 per lane), then columns are selected from LDS — immune to the
// cache-line-utilization penalty that made scattered global reads slow
// (round-8 nt-load regression: 90 us; scattered+cached: ~27; this: ~stream).
// Block->row mapping XCD-aligned (stripe s from XCD s%8, matching gemm1).
__global__ __launch_bounds__(256)
void k_gather(const float* __restrict__ F, const int* __restrict__ idx,
              unsigned short* __restrict__ X) {
  __shared__ int idxs[KD];
  __shared__ float frow[NFEAT];
  int b = blockIdx.x, t = threadIdx.x;
  int row = ((b & 7) << 7) + ((b >> 10) << 10) + ((b >> 3) & 127);
  for (int j = t; j < KD; j += 256) idxs[j] = idx[j];
  const float4* src = (const float4*)(F + (size_t)row * NFEAT);
#pragma unroll
  for (int j = 0; j < 2; ++j)
    *(float4*)(frow + (t + j * 256) * 4) = src[t + j * 256];
  __syncthreads();
  int i0 = t * 4;
  ushort4 o;
  o.x = f2bf(frow[idxs[i0 + 0]]);
  o.y = f2bf(frow[idxs[i0 + 1]]);
  o.z = f2bf(frow[idxs[i0 + 2]]);
  o.w = f2bf(frow[idxs[i0 + 3]]);
  *(ushort4*)(X + (size_t)row * KD + i0) = o;
}

// ============ GEMM1: D = sigmoid(X @ WT^T + b) ============
// m97 structure: 128x128 tile, BK=64, 256 threads = 4 waves (2x2), wave tile
// 64x64 (acc 4x4). Single LDS buffer, 2-phase syncthreads loop.
// T2 XOR-swizzle via pre-swizzled source + swizzled ds_read.
// __launch_bounds__(256,4): 4 blocks/CU (verified: 42 us warm = ~810 TF).
__global__ __launch_bounds__(256, 4)
void k_gemm1(const unsigned short* __restrict__ A, const unsigned short* __restrict__ Bt,
             const float* __restrict__ bias, unsigned short* __restrict__ D) {
  __shared__ __align__(16) unsigned short As[128 * 64];
  __shared__ __align__(16) unsigned short Bs[128 * 64];
  const int t = threadIdx.x;
  const int lane = t & 63;
  const int wave = t >> 6;
  const int m0 = blockIdx.x * 128;
  const int n0 = blockIdx.y * 128;
  const int wm = (wave >> 1) * 64;
  const int wn = (wave & 1) * 64;
  const int cl = lane & 15;
  const int klb = (lane >> 4) * 8;
  const int rsel = (lane & 7) * 8;       // read-side swizzle (elems)

  const int sc = ((t & 7) ^ ((t >> 3) & 7)) * 8;  // pre-swizzled source col
  const unsigned short* Ab = A + (size_t)(m0 + (t >> 3)) * KD + sc;
  const unsigned short* Bb = Bt + (size_t)(n0 + (t >> 3)) * KD + sc;
  unsigned short* const Ad = As + (size_t)(t & ~63) * 8;
  unsigned short* const Bd = Bs + (size_t)(t & ~63) * 8;

  f32x4 acc[4][4];
#pragma unroll
  for (int i = 0; i < 4; ++i)
#pragma unroll
    for (int j = 0; j < 4; ++j) acc[i][j] = (f32x4)0.f;

  for (int kt = 0; kt < KD / 64; ++kt) {
    const int k0 = kt * 64;
#pragma unroll
    for (int j = 0; j < 4; ++j) {
      gload_lds16(Ab + (size_t)j * 32 * KD + k0, Ad + j * 2048);
      gload_lds16(Bb + (size_t)j * 32 * KD + k0, Bd + j * 2048);
    }
    __syncthreads();
#pragma unroll
    for (int kk = 0; kk < 2; ++kk) {
      bf16x8 af[4], bfr[4];
      const int kl = kk * 32 + klb;
#pragma unroll
      for (int n = 0; n < 4; ++n)
        bfr[n] = ld_frag(Bs + (wn + n * 16 + cl) * 64 + (kl ^ rsel));
#pragma unroll
      for (int m = 0; m < 4; ++m)
        af[m] = ld_frag(As + (wm + m * 16 + cl) * 64 + (kl ^ rsel));
      __builtin_amdgcn_s_setprio(1);
#pragma unroll
      for (int m = 0; m < 4; ++m)
#pragma unroll
        for (int n = 0; n < 4; ++n)
          acc[m][n] = __builtin_amdgcn_mfma_f32_16x16x32_bf16(af[m], bfr[n], acc[m][n], 0, 0, 0);
      __builtin_amdgcn_s_setprio(0);
    }
    __syncthreads();
  }

  // epilogue: sigmoid(acc + bias) -> bf16 D
  const int rq = lane >> 4;
#pragma unroll
  for (int n = 0; n < 4; ++n) {
    const int col = n0 + wn + n * 16 + cl;
    const float bv = bias[col];
#pragma unroll
    for (int m = 0; m < 4; ++m) {
      const int rbase = m0 + wm + m * 16 + rq * 4;
#pragma unroll
      for (int i = 0; i < 4; ++i) {
        float v = acc[m][n][i] + bv;
        float s = 1.0f / (1.0f + __expf(-v));
        D[(size_t)(rbase + i) * NNODE + col] = f2bf(s);
      }
    }
  }
}

// ============ k_rg2: fused route + GEMM2, 2 blocks/CU ============
// 512 blocks x 256 threads, 32 batch rows per block. LDS = Mu 64K + Bs 16K
// = 80K exactly -> 2 blocks/CU (launch_bounds(256,2)).
// Phase 1: routing reads d-values DIRECTLY from global D (L2/L3-hot, just
//          written by gemm1), writes mu to XOR-swizzled Mu.
// Phase 2: out = Mu @ PT^T; B reg-prefetched one K-step ahead; nt-store out.
__global__ __launch_bounds__(256, 2)
void k_rg2(const unsigned short* __restrict__ D, const unsigned short* __restrict__ PT,
           float* __restrict__ outF) {
  __shared__ __align__(16) unsigned short Mu[32 * 1024];
  __shared__ __align__(16) unsigned short Bs[128 * 64];
  const int t = threadIdx.x;
  const int lane = t & 63;
  const int wave = t >> 6;
  const int m0 = blockIdx.x * 32;

  // ---- phase 1: route. thread -> (row = t>>3, octant = t&7), 128 leaves.
  {
    const int row = t >> 3;
    const unsigned short* drow = D + (size_t)(m0 + row) * NNODE;
    unsigned short* murow = Mu + row * 1024;
    const int rswz = (row & 7) << 3;            // elem-XOR for this row
    const int lb = (t & 7) * 128;
#pragma unroll
    for (int s = 0; s < 8; ++s) {
      const int lb16 = lb + s * 16;
      float P5 = 1.0f;
#pragma unroll
      for (int k = 0; k < 6; ++k) {
        int node = (1 << k) + (lb16 >> (10 - k));
        float d = bf2f(drow[node]);
        P5 *= ((lb16 >> (9 - k)) & 1) ? (1.0f - d) : d;
      }
#pragma unroll
      for (int gg = 0; gg < 4; ++gg) {
        const int lb4 = lb16 + gg * 4;
        float d6 = bf2f(drow[64 + (lb4 >> 4)]);
        float d7 = bf2f(drow[128 + (lb4 >> 3)]);
        float P7 = P5 * (((lb4 >> 3) & 1) ? (1.0f - d6) : d6)
                      * (((lb4 >> 2) & 1) ? (1.0f - d7) : d7);
        float d8 = bf2f(drow[256 + (lb4 >> 2)]);
        // d9 sibling pair: indices 512+(lb4>>1), +1 -> one aligned 4B load
        unsigned int d9u = *(const unsigned int*)(drow + 512 + (lb4 >> 1));
        float d9a = bf2f((unsigned short)(d9u & 0xFFFFu));
        float d9b = bf2f((unsigned short)(d9u >> 16));
        float P8a = P7 * d8, P8b = P7 * (1.0f - d8);
        ushort4 m4;
        m4.x = f2bf(P8a * d9a);
        m4.y = f2bf(P8a * (1.0f - d9a));
        m4.z = f2bf(P8b * d9b);
        m4.w = f2bf(P8b * (1.0f - d9b));
        *(ushort4*)(murow + (lb4 ^ rswz)) = m4;   // 4-aligned: XOR hits bits 3-5
      }
    }
  }
  __syncthreads();

  // ---- phase 2: GEMM. 4 waves: wm = (wave>>1)*16, wn = (wave&1)*64.
  const int cl = lane & 15;
  const int klb = (lane >> 4) * 8;
  const int rsel = (lane & 7) * 8;        // Bs read swizzle
  const int arsel = (cl & 7) * 8;         // Mu read swizzle (row = wm+cl)
  const int wm = (wave >> 1) * 16;
  const int wn = (wave & 1) * 64;
  // B staging: thread -> row br = t>>1, k-half bh = t&1 (4 chunks of 8).
  const int br = t >> 1, bh = t & 1;
  const unsigned short* Bg = PT + (size_t)br * NNODE + bh * 32;
  unsigned short* bw0 = Bs + br * 64 + (((bh * 4 + 0) ^ (br & 7)) * 8);
  unsigned short* bw1 = Bs + br * 64 + (((bh * 4 + 1) ^ (br & 7)) * 8);
  unsigned short* bw2 = Bs + br * 64 + (((bh * 4 + 2) ^ (br & 7)) * 8);
  unsigned short* bw3 = Bs + br * 64 + (((bh * 4 + 3) ^ (br & 7)) * 8);

  f32x4 acc[4];
#pragma unroll
  for (int n = 0; n < 4; ++n) acc[n] = (f32x4)0.f;

  u32x4 p0 = *(const u32x4*)(Bg + 0);
  u32x4 p1 = *(const u32x4*)(Bg + 8);
  u32x4 p2 = *(const u32x4*)(Bg + 16);
  u32x4 p3 = *(const u32x4*)(Bg + 24);

  for (int kt = 0; kt < 16; ++kt) {
    *(u32x4*)bw0 = p0; *(u32x4*)bw1 = p1; *(u32x4*)bw2 = p2; *(u32x4*)bw3 = p3;
    if (kt < 15) {
      const unsigned short* g = Bg + (kt + 1) * 64;
      p0 = *(const u32x4*)(g + 0);
      p1 = *(const u32x4*)(g + 8);
      p2 = *(const u32x4*)(g + 16);
      p3 = *(const u32x4*)(g + 24);
    }
    __syncthreads();
#pragma unroll
    for (int kk = 0; kk < 2; ++kk) {
      const int kl = kk * 32 + klb;
      bf16x8 a = ld_frag(Mu + (wm + cl) * 1024 + ((kt * 64 + kl) ^ arsel));
      bf16x8 bfr[4];
#pragma unroll
      for (int n = 0; n < 4; ++n)
        bfr[n] = ld_frag(Bs + (wn + n * 16 + cl) * 64 + (kl ^ rsel));
#pragma unroll
      for (int n = 0; n < 4; ++n)
        acc[n] = __builtin_amdgcn_mfma_f32_16x16x32_bf16(a, bfr[n], acc[n], 0, 0, 0);
    }
    __syncthreads();
  }

  const int rq = lane >> 4;
#pragma unroll
  for (int n = 0; n < 4; ++n) {
    int col = wn + n * 16 + cl;
    if (col < NCLS) {
#pragma unroll
      for (int i = 0; i < 4; ++i)
        __builtin_nontemporal_store(acc[n][i],
            &outF[(size_t)(m0 + wm + rq * 4 + i) * NCLS + col]);
    }
  }
}

extern "C" void kernel_launch(void* const* d_in, const int* in_sizes, int n_in,
                              void* d_out, int out_size, void* d_ws, size_t ws_size,
                              hipStream_t stream) {
  const float* features = (const float*)d_in[0]; // [16384][2048]
  const float* mask     = (const float*)d_in[1]; // [1024][2048]
  const float* W        = (const float*)d_in[2]; // [1024][1024]
  const float* bias     = (const float*)d_in[3]; // [1024]
  const float* pi       = (const float*)d_in[4]; // [1024][100]
  float* out = (float*)d_out;                    // [16384][100]

  char* ws = (char*)d_ws;
  int* idx           = (int*)ws;                                    // 4 KiB
  unsigned short* WT = (unsigned short*)(ws + 4096);                // 2 MiB [1024][1024]
  unsigned short* PT = (unsigned short*)(ws + 4096 + (1u << 21));   // 256 KiB [128][1024]
  unsigned short* X  = (unsigned short*)(ws + 4096 + (1u << 21) + (1u << 18)); // 32 MiB
  unsigned short* D  = (unsigned short*)(ws + 4096 + (1u << 21) + (1u << 18) + (1u << 25)); // 32 MiB

  // Small preps first; gather last before gemm1 so X is the freshest data in
  // cache (round-5/6 measurement: gemm1 42 us warm vs ~70 us cold).
  k_idx<<<dim3(KD), dim3(256), 0, stream>>>(mask, idx);
  k_wt<<<dim3(32, 32), dim3(32, 8), 0, stream>>>(W, WT);
  k_probs<<<dim3(NNODE), dim3(64), 0, stream>>>(pi, PT);
  k_gather<<<dim3(BATCH), dim3(256), 0, stream>>>(features, idx, X);
  k_gemm1<<<dim3(BATCH / 128, NNODE / 128), dim3(256), 0, stream>>>(X, WT, bias, D);
  k_rg2<<<dim3(BATCH / 32), dim3(256), 0, stream>>>(D, PT, out);
}